// Round 1
// baseline (5271.077 us; speedup 1.0000x reference)
//
#include <hip/hip_runtime.h>
#include <cstddef>
#include <cstdint>

// Problem constants (SerGINE)
#define NA_C 200000
#define NF_C 50000
#define EA_C 800000
#define EF_C 200000
#define NG_C 4096
#define DD 128   // node feature dim
#define HH 256   // hidden dim (2*D)

// ---------------------------------------------------------------------------
// Generic fp32 GEMM: C = op(A) @ W + bias [+ Cadd]
//   op(A): v = A[m,k]; if Aadd v += Aadd[m,k]; if rowscale v *= rowscale[m];
//          if iscale  v = relu(v*iscale[k] + ishift[k])   (fused BN+relu read)
// 128x128 tile, BK=8, 256 threads, 8x8 micro-tile per thread.
// ---------------------------------------------------------------------------
__global__ __launch_bounds__(256) void gemm_f32(
    const float* __restrict__ A, const float* __restrict__ Aadd,
    const float* __restrict__ rowscale,
    const float* __restrict__ iscale, const float* __restrict__ ishift,
    const float* __restrict__ W, const float* __restrict__ bias,
    const float* __restrict__ Cadd, float* __restrict__ C,
    int M, int K, int N)
{
    __shared__ float As[8][132];   // transposed: As[k][m], row stride 132 (16B-aligned rows)
    __shared__ float Bs[8][132];
    const int tid = threadIdx.x;
    const int tx = tid & 15;       // m-group
    const int ty = tid >> 4;       // n-group
    const int m0 = blockIdx.y * 128;
    const int n0 = blockIdx.x * 128;

    float acc[8][8];
#pragma unroll
    for (int i = 0; i < 8; ++i)
#pragma unroll
        for (int j = 0; j < 8; ++j) acc[i][j] = 0.f;

    const int ar = tid >> 1;          // 0..127 tile row
    const int ak = (tid & 1) * 4;     // 0 or 4
    const int br = tid >> 5;          // 0..7 tile k-row
    const int bc = (tid & 31) * 4;    // 0..124

    for (int k0 = 0; k0 < K; k0 += 8) {
        // stage A (with fused input transform), write transposed
#pragma unroll
        for (int j = 0; j < 4; ++j) {
            int m = m0 + ar, k = k0 + ak + j;
            float v = 0.f;
            if (m < M && k < K) {
                size_t idx = (size_t)m * K + k;
                v = A[idx];
                if (Aadd) v += Aadd[idx];
                if (rowscale) v *= rowscale[m];
                if (iscale) v = fmaxf(fmaf(v, iscale[k], ishift[k]), 0.f);
            }
            As[ak + j][ar] = v;
        }
        // stage B
        {
            int k = k0 + br;
            float4 v = make_float4(0.f, 0.f, 0.f, 0.f);
            if (k < K) v = *(const float4*)&W[(size_t)k * N + n0 + bc];
            *(float4*)&Bs[br][bc] = v;
        }
        __syncthreads();
#pragma unroll
        for (int kk = 0; kk < 8; ++kk) {
            float a[8], b[8];
            *(float4*)&a[0] = *(const float4*)&As[kk][tx * 8];
            *(float4*)&a[4] = *(const float4*)&As[kk][tx * 8 + 4];
            *(float4*)&b[0] = *(const float4*)&Bs[kk][ty * 8];
            *(float4*)&b[4] = *(const float4*)&Bs[kk][ty * 8 + 4];
#pragma unroll
            for (int i = 0; i < 8; ++i)
#pragma unroll
                for (int j = 0; j < 8; ++j)
                    acc[i][j] = fmaf(a[i], b[j], acc[i][j]);
        }
        __syncthreads();
    }

    const int row0 = m0 + tx * 8, col0 = n0 + ty * 8;
#pragma unroll
    for (int i = 0; i < 8; ++i) {
        int m = row0 + i;
        if (m < M) {
            size_t base = (size_t)m * N + col0;
#pragma unroll
            for (int j = 0; j < 8; ++j) {
                float v = acc[i][j] + bias[col0 + j];
                if (Cadd) v += Cadd[base + j];
                C[base + j] = v;
            }
        }
    }
}

static inline void gemm_launch(hipStream_t s,
    const float* A, const float* Aadd, const float* rowscale,
    const float* iscale, const float* ishift,
    const float* W, const float* bias, const float* Cadd, float* C,
    int M, int K, int N)
{
    dim3 grid(N / 128, (M + 127) / 128);
    gemm_f32<<<grid, dim3(256), 0, s>>>(A, Aadd, rowscale, iscale, ishift, W, bias, Cadd, C, M, K, N);
}

// ---------------------------------------------------------------------------
// Fused GINE message + scatter: agg[dst] += relu(x[src] + attr[e] @ Wm + bm)
// Edge-MLP weights staged in LDS (KE*128 fp32). 2 edges per 256-thread block
// iteration, grid-stride over edges.
// ---------------------------------------------------------------------------
template <int KE>
__global__ __launch_bounds__(256) void msg_scatter(
    const float* __restrict__ x, const float* __restrict__ attr,
    const int* __restrict__ src, const int* __restrict__ dst,
    const float* __restrict__ Wm, const float* __restrict__ bm,
    float* __restrict__ agg, int E)
{
    __shared__ float sW[KE * 128];
    __shared__ float sb[128];
    __shared__ float sattr[2][KE];
    const int tid = threadIdx.x;
    for (int i = tid; i < KE * 128; i += 256) sW[i] = Wm[i];
    if (tid < 128) sb[tid] = bm[tid];
    const int lane = tid & 127;
    const int w = tid >> 7;   // which edge of the pair

    for (int e0 = blockIdx.x * 2; e0 < E; e0 += gridDim.x * 2) {
        __syncthreads();   // protect sW (first iter) and sattr reuse
        if (tid < 2 * KE) {
            int ee = e0 + tid / KE;
            if (ee < E) sattr[tid / KE][tid % KE] = attr[(size_t)ee * KE + (tid % KE)];
        }
        __syncthreads();
        int e = e0 + w;
        if (e < E) {
            float acc = sb[lane];
#pragma unroll
            for (int k = 0; k < KE; ++k)
                acc = fmaf(sattr[w][k], sW[k * 128 + lane], acc);
            float v = x[(size_t)src[e] * 128 + lane] + acc;
            v = fmaxf(v, 0.f);
            atomicAdd(&agg[(size_t)dst[e] * 128 + lane], v);
        }
    }
}

// Column sums / sums-of-squares for BN stats (block = 128 rows x N cols)
__global__ void colstats(const float* __restrict__ X, int M, int N,
                         float* __restrict__ sum, float* __restrict__ sumsq)
{
    int c = threadIdx.x;
    int r0 = blockIdx.x * 128;
    int rend = min(r0 + 128, M);
    float s = 0.f, q = 0.f;
    for (int r = r0; r < rend; ++r) {
        float v = X[(size_t)r * N + c];
        s += v;
        q = fmaf(v, v, q);
    }
    atomicAdd(&sum[c], s);
    atomicAdd(&sumsq[c], q);
}

// scale = g*rsqrt(var+eps); shift = be - mean*scale
__global__ void bn_finalize(const float* __restrict__ sum, const float* __restrict__ sumsq,
                            const float* __restrict__ g, const float* __restrict__ be,
                            float minv, float* __restrict__ sc, float* __restrict__ sh, int N)
{
    int c = threadIdx.x;
    if (c < N) {
        float m = sum[c] * minv;
        float v = fmaxf(sumsq[c] * minv - m * m, 0.f);
        float s = g[c] * rsqrtf(v + 1e-5f);
        sc[c] = s;
        sh[c] = fmaf(-m, s, be[c]);
    }
}

// x = [relu](scale[c]*x + shift[c]), N fixed at 128, float4-vectorized
__global__ void bn_apply(float* __restrict__ X, const float* __restrict__ sc,
                         const float* __restrict__ sh, int relu, size_t n4)
{
    size_t i = (size_t)blockIdx.x * 256 + threadIdx.x;
    if (i >= n4) return;
    size_t base = i * 4;
    int c = (int)(base & 127);
    float4 v = *(float4*)&X[base];
    v.x = fmaf(v.x, sc[c],     sh[c]);
    v.y = fmaf(v.y, sc[c + 1], sh[c + 1]);
    v.z = fmaf(v.z, sc[c + 2], sh[c + 2]);
    v.w = fmaf(v.w, sc[c + 3], sh[c + 3]);
    if (relu) {
        v.x = fmaxf(v.x, 0.f); v.y = fmaxf(v.y, 0.f);
        v.z = fmaxf(v.z, 0.f); v.w = fmaxf(v.w, 0.f);
    }
    *(float4*)&X[base] = v;
}

// a += b (float4)
__global__ void add4(float* __restrict__ a, const float* __restrict__ b, size_t n4)
{
    size_t i = (size_t)blockIdx.x * 256 + threadIdx.x;
    if (i >= n4) return;
    size_t base = i * 4;
    float4 va = *(float4*)&a[base];
    float4 vb = *(const float4*)&b[base];
    va.x += vb.x; va.y += vb.y; va.z += vb.z; va.w += vb.w;
    *(float4*)&a[base] = va;
}

// sums[fidx[v]] += h[aidx[v]]; cnt[fidx[v]] += 1   (thread per (v, channel))
__global__ void a2f_gather(const float* __restrict__ h, const int* __restrict__ aidx,
                           const int* __restrict__ fidx, float* __restrict__ sums,
                           float* __restrict__ cnt, int n)
{
    size_t gid = (size_t)blockIdx.x * 256 + threadIdx.x;
    int v = (int)(gid >> 7), c = (int)(gid & 127);
    if (v < n) {
        int f = fidx[v];
        atomicAdd(&sums[(size_t)f * 128 + c], h[(size_t)aidx[v] * 128 + c]);
        if (c == 0) atomicAdd(&cnt[f], 1.f);
    }
}

__global__ void inv_cnt(const float* __restrict__ cnt, float* __restrict__ rs, int n)
{
    int i = blockIdx.x * 256 + threadIdx.x;
    if (i < n) rs[i] = 1.f / fmaxf(cnt[i], 1.f);
}

// out[seg[v]] += x[v]; cnt[seg[v]] += 1
__global__ void seg_scatter(const float* __restrict__ x, const int* __restrict__ seg,
                            float* __restrict__ out, float* __restrict__ cnt, int n)
{
    size_t gid = (size_t)blockIdx.x * 256 + threadIdx.x;
    int v = (int)(gid >> 7), c = (int)(gid & 127);
    if (v < n) {
        int s = seg[v];
        atomicAdd(&out[(size_t)s * 128 + c], x[(size_t)v * 128 + c]);
        if (c == 0) atomicAdd(&cnt[s], 1.f);
    }
}

__global__ void final_div(float* __restrict__ out, const float* __restrict__ cnt, int total)
{
    int i = blockIdx.x * 256 + threadIdx.x;
    if (i < total) out[i] = out[i] / fmaxf(cnt[i >> 7], 1.f);
}

// ---------------------------------------------------------------------------
// WS layout (floats):
//   h   [0, NA*128)                                  102.4 MB  (also holds g)
//   R2  [NA*128, NA*128 + NA*256)                    204.8 MB  (agg/t/sums/a2f_lin/gt)
//   small stats area after that (~0.4 MB): sum,sq,scale,shift(256 ea), cnt(NF), rs(NF)
// Total ~307.6 MB.
// ---------------------------------------------------------------------------
extern "C" void kernel_launch(void* const* d_in, const int* in_sizes, int n_in,
                              void* d_out, int out_size, void* d_ws, size_t ws_size,
                              hipStream_t stream)
{
    const float* atom_x        = (const float*)d_in[0];
    const float* fg_x          = (const float*)d_in[1];
    const float* atom_edge_attr= (const float*)d_in[2];
    const float* fg_edge_attr  = (const float*)d_in[3];
    const float* atom_emb_W    = (const float*)d_in[4];
    const float* atom_emb_b    = (const float*)d_in[5];
    const float* fg_emb_W      = (const float*)d_in[6];
    const float* fg_emb_b      = (const float*)d_in[7];
    const float* bond_W        = (const float*)d_in[8];
    const float* bond_b        = (const float*)d_in[9];
    const float* ag_W1         = (const float*)d_in[10];
    const float* ag_b1         = (const float*)d_in[11];
    const float* ag_g1         = (const float*)d_in[12];
    const float* ag_be1        = (const float*)d_in[13];
    const float* ag_W2         = (const float*)d_in[14];
    const float* ag_b2         = (const float*)d_in[15];
    const float* abn_g         = (const float*)d_in[16];
    const float* abn_b         = (const float*)d_in[17];
    const float* fge_W         = (const float*)d_in[18];
    const float* fge_b         = (const float*)d_in[19];
    const float* fg_W1         = (const float*)d_in[20];
    const float* fg_b1         = (const float*)d_in[21];
    const float* fg_g1         = (const float*)d_in[22];
    const float* fg_be1        = (const float*)d_in[23];
    const float* fg_W2         = (const float*)d_in[24];
    const float* fg_b2         = (const float*)d_in[25];
    const float* fbn_g         = (const float*)d_in[26];
    const float* fbn_b         = (const float*)d_in[27];
    const float* a2f_W         = (const float*)d_in[28];
    const float* a2f_b         = (const float*)d_in[29];
    const int*   aei           = (const int*)d_in[30];
    const int*   fei           = (const int*)d_in[31];
    const int*   atom_idx      = (const int*)d_in[32];
    const int*   fg_idx        = (const int*)d_in[33];
    const int*   fg_batch      = (const int*)d_in[34];
    const int *asrc = aei, *adst = aei + EA_C;
    const int *fsrc = fei, *fdst = fei + EF_C;

    float* ws  = (float*)d_ws;
    float* h   = ws;                                 // NA*128
    float* R2  = ws + (size_t)NA_C * DD;             // NA*256 reuse region
    float* sm  = R2 + (size_t)NA_C * HH;
    float* s_sum = sm;
    float* s_sq  = sm + 256;
    float* s_sc  = sm + 512;
    float* s_sh  = sm + 768;
    float* cnt   = sm + 1024;      // NF floats (also NG for final)
    float* rs    = cnt + NF_C;     // NF floats

    // 1) atom embedding: h = atom_x @ atom_emb_W + b
    gemm_launch(stream, atom_x, nullptr, nullptr, nullptr, nullptr,
                atom_emb_W, atom_emb_b, nullptr, h, NA_C, 101, DD);

    // 2) three atom GINE layers
    for (int i = 0; i < 3; ++i) {
        float* agg = R2;
        hipMemsetAsync(agg, 0, (size_t)NA_C * DD * sizeof(float), stream);
        msg_scatter<11><<<dim3(16384), dim3(256), 0, stream>>>(
            h, atom_edge_attr, asrc, adst,
            bond_W + (size_t)i * 11 * DD, bond_b + i * DD, agg, EA_C);
        add4<<<dim3((NA_C * DD / 4 + 255) / 256), dim3(256), 0, stream>>>(
            h, agg, (size_t)NA_C * DD / 4);          // h = h + agg (frees agg for t)
        float* t = R2;
        gemm_launch(stream, h, nullptr, nullptr, nullptr, nullptr,
                    ag_W1 + (size_t)i * DD * HH, ag_b1 + i * HH, nullptr, t, NA_C, DD, HH);
        hipMemsetAsync(s_sum, 0, 512 * sizeof(float), stream);
        colstats<<<dim3((NA_C + 127) / 128), dim3(HH), 0, stream>>>(t, NA_C, HH, s_sum, s_sq);
        bn_finalize<<<dim3(1), dim3(HH), 0, stream>>>(
            s_sum, s_sq, ag_g1 + i * HH, ag_be1 + i * HH, 1.f / NA_C, s_sc, s_sh, HH);
        // h = relu(bn(t)) @ W2 + b2   (bn+relu fused into GEMM A-read)
        gemm_launch(stream, t, nullptr, nullptr, s_sc, s_sh,
                    ag_W2 + (size_t)i * HH * DD, ag_b2 + i * DD, nullptr, h, NA_C, HH, DD);
        hipMemsetAsync(s_sum, 0, 512 * sizeof(float), stream);
        colstats<<<dim3((NA_C + 127) / 128), dim3(DD), 0, stream>>>(h, NA_C, DD, s_sum, s_sq);
        bn_finalize<<<dim3(1), dim3(DD), 0, stream>>>(
            s_sum, s_sq, abn_g + i * DD, abn_b + i * DD, 1.f / NA_C, s_sc, s_sh, DD);
        bn_apply<<<dim3((NA_C * DD / 4 + 255) / 256), dim3(256), 0, stream>>>(
            h, s_sc, s_sh, (int)(i != 2), (size_t)NA_C * DD / 4);
    }

    // 3) atom -> fg: a2f = seg_mean(h[atom_idx], fg_idx) @ a2f_W + a2f_b
    float* sums = R2;
    hipMemsetAsync(sums, 0, (size_t)NF_C * DD * sizeof(float), stream);
    hipMemsetAsync(cnt, 0, NF_C * sizeof(float), stream);
    a2f_gather<<<dim3(NA_C * DD / 256), dim3(256), 0, stream>>>(
        h, atom_idx, fg_idx, sums, cnt, NA_C);
    inv_cnt<<<dim3((NF_C + 255) / 256), dim3(256), 0, stream>>>(cnt, rs, NF_C);
    float* a2f_lin = R2 + (size_t)NF_C * DD;
    gemm_launch(stream, sums, nullptr, rs, nullptr, nullptr,
                a2f_W, a2f_b, nullptr, a2f_lin, NF_C, DD, DD);

    // 4) fg embedding: g = fg_x @ fg_emb_W + b + a2f_lin   (g lives in h region)
    float* g = h;
    gemm_launch(stream, fg_x, nullptr, nullptr, nullptr, nullptr,
                fg_emb_W, fg_emb_b, a2f_lin, g, NF_C, 73, DD);

    // 5) two fg GINE layers
    for (int i = 0; i < 2; ++i) {
        float* gagg = R2;
        hipMemsetAsync(gagg, 0, (size_t)NF_C * DD * sizeof(float), stream);
        msg_scatter<101><<<dim3(4096), dim3(256), 0, stream>>>(
            g, fg_edge_attr, fsrc, fdst,
            fge_W + (size_t)i * 101 * DD, fge_b + i * DD, gagg, EF_C);
        add4<<<dim3((NF_C * DD / 4 + 255) / 256), dim3(256), 0, stream>>>(
            g, gagg, (size_t)NF_C * DD / 4);
        float* gt = R2;
        gemm_launch(stream, g, nullptr, nullptr, nullptr, nullptr,
                    fg_W1 + (size_t)i * DD * HH, fg_b1 + i * HH, nullptr, gt, NF_C, DD, HH);
        hipMemsetAsync(s_sum, 0, 512 * sizeof(float), stream);
        colstats<<<dim3((NF_C + 127) / 128), dim3(HH), 0, stream>>>(gt, NF_C, HH, s_sum, s_sq);
        bn_finalize<<<dim3(1), dim3(HH), 0, stream>>>(
            s_sum, s_sq, fg_g1 + i * HH, fg_be1 + i * HH, 1.f / NF_C, s_sc, s_sh, HH);
        gemm_launch(stream, gt, nullptr, nullptr, s_sc, s_sh,
                    fg_W2 + (size_t)i * HH * DD, fg_b2 + i * DD, nullptr, g, NF_C, HH, DD);
        hipMemsetAsync(s_sum, 0, 512 * sizeof(float), stream);
        colstats<<<dim3((NF_C + 127) / 128), dim3(DD), 0, stream>>>(g, NF_C, DD, s_sum, s_sq);
        bn_finalize<<<dim3(1), dim3(DD), 0, stream>>>(
            s_sum, s_sq, fbn_g + i * DD, fbn_b + i * DD, 1.f / NF_C, s_sc, s_sh, DD);
        bn_apply<<<dim3((NF_C * DD / 4 + 255) / 256), dim3(256), 0, stream>>>(
            g, s_sc, s_sh, (int)(i != 1), (size_t)NF_C * DD / 4);
    }

    // 6) final: out = seg_mean(g, fg_batch, NG)
    float* out = (float*)d_out;
    hipMemsetAsync(out, 0, (size_t)NG_C * DD * sizeof(float), stream);
    hipMemsetAsync(cnt, 0, NG_C * sizeof(float), stream);
    seg_scatter<<<dim3(NF_C * DD / 256), dim3(256), 0, stream>>>(g, fg_batch, out, cnt, NF_C);
    final_div<<<dim3((NG_C * DD + 255) / 256), dim3(256), 0, stream>>>(out, cnt, NG_C * DD);
}